// Round 6
// baseline (2400.798 us; speedup 1.0000x reference)
//
#include <hip/hip_runtime.h>
#include <stdint.h>

#define B_ 8
#define D_ 128
#define T_ 4096
#define Q_ 30
#define C_ 1024

typedef __attribute__((ext_vector_type(8))) _Float16 half8;
typedef __attribute__((ext_vector_type(4))) float float4_;
typedef __attribute__((ext_vector_type(2))) float float2_;

// row-major fp16 codebook image [Q*C][128] — B-fragments load straight from here.
__device__ __align__(16) _Float16 g_half[(size_t)Q_*C_*D_];

// ---------------- prep 1: per-code ||c||^2, fp64 accumulation ----------------
__global__ void rvq_prep(const float* __restrict__ cb, float* __restrict__ sumsq){
  int g    = blockIdx.x*128 + (threadIdx.x>>1);
  int half = threadIdx.x & 1;
  const float* src = cb + (size_t)g*D_ + half*64;
  double s = 0.0;
#pragma unroll
  for (int i=0;i<64;i+=4){
    float4_ f = *(const float4_*)(src+i);
    s += (double)f.x*f.x + (double)f.y*f.y + (double)f.z*f.z + (double)f.w*f.w;
  }
  s += __shfl_xor(s, 1);
  if (!half) sumsq[g] = (float)s;
}

// ---------------- prep 2: fp32 -> fp16 codebook, row-major -------------------
__global__ void rvq_h(const float* __restrict__ cb){
  const size_t i = ((size_t)blockIdx.x*256 + threadIdx.x)*8;
  float4_ f0 = *(const float4_*)(cb + i);
  float4_ f1 = *(const float4_*)(cb + i + 4);
  half8 h;
  h[0]=(_Float16)f0.x; h[1]=(_Float16)f0.y; h[2]=(_Float16)f0.z; h[3]=(_Float16)f0.w;
  h[4]=(_Float16)f1.x; h[5]=(_Float16)f1.y; h[6]=(_Float16)f1.z; h[7]=(_Float16)f1.w;
  *(half8*)(g_half + i) = h;
}

// --- main: 30-step RVQ, 32 rows/wave, 256 blocks (R0 structure, verified 1562us).
// R1-R5 lesson: 32 rows/wave caps the machine at 1 wave/SIMD (1024 waves total);
// every 16-row 2-wave variant lost (tail issue doubles per SIMD). So optimize
// issue count + dependent chains WITHIN the 1-wave structure:
//  - top-2 insert = min + med3 (branch-free, 2 ops vs ~5)
//  - top-4 scan   = min + 3x med3, branch-free, ids fully packed (10 bits in
//    score mantissa; perturbation 2^-13 << fp16 score error; fp64 rescore
//    still decides the winner exactly)
//  - fp64 rescore: 4 candidates in parallel (4x shorter dependent chains),
//    registers are plentiful at 1 wave/SIMD (pool 512/lane, no spill)
__global__ __launch_bounds__(256) void rvq_main(
    const float* __restrict__ x, const float* __restrict__ cb,
    const float* __restrict__ sumsq, double* __restrict__ lossAcc,
    float* __restrict__ out)
{
  __shared__ float sCS[4][32][36];   // per-wave packed top2 scores (stride 36 = 16B-aligned rows)
  __shared__ int   sI4[4][32][4];    // per-row top-4 global code ids

  const int tid  = threadIdx.x;
  const int wv   = tid>>6;
  const int ln   = tid&63;
  const int col  = ln&15;
  const int quad = ln>>4;
  const int blk  = blockIdx.x;
  const int b    = blk>>5;
  const int t0   = ((blk&31)<<7) + (wv<<5);

  // residual fp64, A-frag distribution: row = rt*16+col, dim = kc*32+quad*8+j
  double rmast[2][4][8];
#pragma unroll
  for (int rt=0;rt<2;++rt){
    const int t = t0 + rt*16 + col;
#pragma unroll
    for (int kc=0;kc<4;++kc)
#pragma unroll
      for (int j=0;j<8;++j){
        const int d = kc*32 + quad*8 + j;
        rmast[rt][kc][j] = (double)x[((size_t)b*D_ + d)*T_ + t];
      }
  }

  half8 ah[2][4];
  auto makeAB = [&](){
#pragma unroll
    for (int rt=0;rt<2;++rt)
#pragma unroll
      for (int kc=0;kc<4;++kc){
        half8 h;
#pragma unroll
        for (int j=0;j<8;++j) h[j] = (_Float16)(float)rmast[rt][kc][j];
        ah[rt][kc] = h;
      }
  };
  makeAB();

  double lossd = 0.0;

  // register pipeline buffers: B-fragments + cc for one group (32 codes)
  half8 bufA[8], bufB[8];
  float ccA[2],  ccB[2];

  const _Float16* cbh0 = g_half;
  const float*    ssq0 = sumsq;

  auto loadGroup = [&](const _Float16* cbh, const float* ssq, int g, half8* Bv, float* cc){
#pragma unroll
    for (int kc=0;kc<4;++kc)
#pragma unroll
      for (int ct=0;ct<2;++ct){
        const int n = g*32 + ct*16 + col;
        Bv[kc*2+ct] = *(const half8*)(cbh + n*128 + kc*32 + quad*8);
      }
#pragma unroll
    for (int ct=0;ct<2;++ct)
      cc[ct] = ssq[(g*2+ct)*16 + col];
  };

  loadGroup(cbh0, ssq0, 0, bufA, ccA);   // prologue: q=0, group 0

  for (int q=0;q<Q_;++q){
    const float*    cbq = cb    + (size_t)q*C_*D_;
    const _Float16* cbh = g_half + (size_t)q*C_*D_;
    const float*    ssq = sumsq + q*C_;

    // packed top-2 per cell: score float with low 10 mantissa bits = full code id
    float p1[2][4], p2[2][4];
#pragma unroll
    for (int rt=0;rt<2;++rt)
#pragma unroll
      for (int rg=0;rg<4;++rg){ p1[rt][rg]=3.0e38f; p2[rt][rg]=3.0e38f; }

#pragma unroll
    for (int g=0; g<32; ++g){
      half8* cur = (g&1) ? bufB : bufA;
      float* ccc = (g&1) ? ccB  : ccA;
      // prefetch next group (codebook loads independent of residual —
      // cross-q prefetch of (q+1, group 0) overlaps the q-tail)
      if (g < 31){
        loadGroup(cbh, ssq, g+1, (g&1)?bufA:bufB, (g&1)?ccA:ccB);
      } else if (q+1 < Q_){
        loadGroup(cbh + C_*D_, ssq + C_, 0, (g&1)?bufA:bufB, (g&1)?ccA:ccB);
      }

      float4_ acc[2][2];
#pragma unroll
      for (int a=0;a<2;++a)
#pragma unroll
        for (int c2=0;c2<2;++c2) acc[a][c2] = (float4_){0.f,0.f,0.f,0.f};
#pragma unroll
      for (int kc=0;kc<4;++kc)
#pragma unroll
        for (int rt=0;rt<2;++rt)
#pragma unroll
          for (int ct=0;ct<2;++ct)
            acc[rt][ct] = __builtin_amdgcn_mfma_f32_16x16x32_f16(ah[rt][kc], cur[kc*2+ct], acc[rt][ct], 0,0,0);

#pragma unroll
      for (int ct=0;ct<2;++ct){
        // full 10-bit code id = (g*2+ct)*16 + col; high 6 bits compile-time
        const unsigned idc = ((unsigned)(g*2+ct))<<4;
#pragma unroll
        for (int rt=0;rt<2;++rt)
#pragma unroll
          for (int rg=0;rg<4;++rg){
            float sc = fmaf(-2.0f, acc[rt][ct][rg], ccc[ct]);
            unsigned u = (__builtin_bit_cast(unsigned, sc) & ~1023u) | idc | (unsigned)col;
            float sp = __builtin_bit_cast(float, u);
            // branch-free sorted-pair insert
            p2[rt][rg] = __builtin_amdgcn_fmed3f(sp, p1[rt][rg], p2[rt][rg]);
            p1[rt][rg] = fminf(sp, p1[rt][rg]);
          }
      }
    }

    // ---- publish per-lane packed top-2 (wave-private, lockstep) ----
#pragma unroll
    for (int rt=0;rt<2;++rt)
#pragma unroll
      for (int rg=0;rg<4;++rg){
        const int row = rt*16 + quad*4 + rg;
        *(float2_*)&sCS[wv][row][col*2] = (float2_){p1[rt][rg], p2[rt][rg]};
      }

    // ---- lanes 0..31: branch-free top-4 of own row's 32 packed entries ----
    if (ln < 32){
      const int row = ln;
      float b0=3.0e38f,b1=3.0e38f,b2=3.0e38f,b3=3.0e38f;
#pragma unroll
      for (int i=0;i<8;++i){
        float4_ v = *(const float4_*)&sCS[wv][row][i*4];
#pragma unroll
        for (int k2=0;k2<4;++k2){
          const float sc = v[k2];
          // sorted insert into (b0<=b1<=b2<=b3), ids ride in low bits
          b3 = __builtin_amdgcn_fmed3f(sc, b2, b3);
          b2 = __builtin_amdgcn_fmed3f(sc, b1, b2);
          b1 = __builtin_amdgcn_fmed3f(sc, b0, b1);
          b0 = fminf(sc, b0);
        }
      }
      sI4[wv][row][0] = (int)(__builtin_bit_cast(unsigned, b0) & 1023u);
      sI4[wv][row][1] = (int)(__builtin_bit_cast(unsigned, b1) & 1023u);
      sI4[wv][row][2] = (int)(__builtin_bit_cast(unsigned, b2) & 1023u);
      sI4[wv][row][3] = (int)(__builtin_bit_cast(unsigned, b3) & 1023u);
    }

    // ---- fp64 exact rescore of top-4, 4 candidates in parallel --------------
#pragma unroll
    for (int rt=0;rt<2;++rt){
      const int m = rt*16 + col;
      const int jj0 = sI4[wv][m][0];
      const int jj1 = sI4[wv][m][1];
      const int jj2 = sI4[wv][m][2];
      const int jj3 = sI4[wv][m][3];
      double sd0=0.0, sd1=0.0, sd2=0.0, sd3=0.0;
#pragma unroll
      for (int kc=0;kc<4;++kc){
        float fv0[8], fv1[8], fv2[8], fv3[8];
        {
          const float* q0 = cbq + ((size_t)jj0<<7) + (quad<<3) + kc*32;
          const float* q1 = cbq + ((size_t)jj1<<7) + (quad<<3) + kc*32;
          const float* q2 = cbq + ((size_t)jj2<<7) + (quad<<3) + kc*32;
          const float* q3 = cbq + ((size_t)jj3<<7) + (quad<<3) + kc*32;
          float4_ a0 = *(const float4_*)(q0), a1 = *(const float4_*)(q0+4);
          float4_ b0v= *(const float4_*)(q1), b1v= *(const float4_*)(q1+4);
          float4_ c0 = *(const float4_*)(q2), c1 = *(const float4_*)(q2+4);
          float4_ d0 = *(const float4_*)(q3), d1 = *(const float4_*)(q3+4);
          fv0[0]=a0.x;fv0[1]=a0.y;fv0[2]=a0.z;fv0[3]=a0.w;fv0[4]=a1.x;fv0[5]=a1.y;fv0[6]=a1.z;fv0[7]=a1.w;
          fv1[0]=b0v.x;fv1[1]=b0v.y;fv1[2]=b0v.z;fv1[3]=b0v.w;fv1[4]=b1v.x;fv1[5]=b1v.y;fv1[6]=b1v.z;fv1[7]=b1v.w;
          fv2[0]=c0.x;fv2[1]=c0.y;fv2[2]=c0.z;fv2[3]=c0.w;fv2[4]=c1.x;fv2[5]=c1.y;fv2[6]=c1.z;fv2[7]=c1.w;
          fv3[0]=d0.x;fv3[1]=d0.y;fv3[2]=d0.z;fv3[3]=d0.w;fv3[4]=d1.x;fv3[5]=d1.y;fv3[6]=d1.z;fv3[7]=d1.w;
        }
#pragma unroll
        for (int j=0;j<8;++j){
          const double r2 = 2.0 * rmast[rt][kc][j];
          double cd;
          cd = (double)fv0[j]; sd0 += cd*(cd - r2);
          cd = (double)fv1[j]; sd1 += cd*(cd - r2);
          cd = (double)fv2[j]; sd2 += cd*(cd - r2);
          cd = (double)fv3[j]; sd3 += cd*(cd - r2);
        }
      }
      sd0 += __shfl_xor(sd0,16); sd0 += __shfl_xor(sd0,32);
      sd1 += __shfl_xor(sd1,16); sd1 += __shfl_xor(sd1,32);
      sd2 += __shfl_xor(sd2,16); sd2 += __shfl_xor(sd2,32);
      sd3 += __shfl_xor(sd3,16); sd3 += __shfl_xor(sd3,32);

      double bestS = sd0; int bestJ = jj0;
      if ((sd1 < bestS) || (sd1 == bestS && jj1 < bestJ)){ bestS = sd1; bestJ = jj1; }
      if ((sd2 < bestS) || (sd2 == bestS && jj2 < bestJ)){ bestS = sd2; bestJ = jj2; }
      if ((sd3 < bestS) || (sd3 == bestS && jj3 < bestJ)){ bestS = sd3; bestJ = jj3; }

      const float* pw = cbq + ((size_t)bestJ<<7) + (quad<<3);
#pragma unroll
      for (int kc=0;kc<4;++kc){
        float4_ w0 = *(const float4_*)(pw + kc*32);
        float4_ w1 = *(const float4_*)(pw + kc*32 + 4);
        float fw[8] = {w0.x,w0.y,w0.z,w0.w,w1.x,w1.y,w1.z,w1.w};
#pragma unroll
        for (int j=0;j<8;++j){
          double rn = rmast[rt][kc][j] - (double)fw[j];
          rmast[rt][kc][j] = rn;
          lossd += rn*rn;
        }
      }
    }
    makeAB();
  }

  // ---- epilogue: quantized = x - r_final ----
#pragma unroll
  for (int rt=0;rt<2;++rt){
    const int t = t0 + rt*16 + col;
#pragma unroll
    for (int kc=0;kc<4;++kc)
#pragma unroll
      for (int j=0;j<8;++j){
        const int d = kc*32 + quad*8 + j;
        const size_t o = ((size_t)b*D_ + d)*T_ + t;
        out[o] = (float)((double)x[o] - rmast[rt][kc][j]);
      }
  }
#pragma unroll
  for (int mk=1; mk<64; mk<<=1) lossd += __shfl_xor(lossd, mk);
  if (ln==0) atomicAdd(lossAcc, lossd);
}

__global__ void rvq_fin(const double* __restrict__ lossAcc, float* __restrict__ out){
  out[(size_t)B_*D_*T_] = (float)(*lossAcc * (1.0/((double)B_*(double)D_*(double)T_)));
}

extern "C" void kernel_launch(void* const* d_in, const int* in_sizes, int n_in,
                              void* d_out, int out_size, void* d_ws, size_t ws_size,
                              hipStream_t stream) {
  const float* x  = (const float*)d_in[0];   // [B, D, T] fp32
  const float* cb = (const float*)d_in[1];   // [Q, C, D] fp32
  float* out      = (float*)d_out;           // [B*D*T] quantized + [1] loss
  double* lossAcc = (double*)d_ws;
  float*  sumsq   = (float*)((char*)d_ws + 256);   // Q*C floats

  hipMemsetAsync(d_ws, 0, 256, stream);
  rvq_prep<<<Q_*C_/128, 256, 0, stream>>>(cb, sumsq);
  rvq_h   <<<(Q_*C_*D_)/(256*8), 256, 0, stream>>>(cb);
  rvq_main<<<(B_*T_)/128, 256, 0, stream>>>(x, cb, sumsq, lossAcc, out);
  rvq_fin <<<1, 1, 0, stream>>>(lossAcc, out);
}